// Round 14
// baseline (264.490 us; speedup 1.0000x reference)
//
#include <hip/hip_runtime.h>
#include <hip/hip_bf16.h>

#define N_NODES 100000
#define FIN 128
#define HID 16
#define NCLS 40
#define NEDGE 3200000
#define NBUCK 391     // ceil(100000/256): 256 dst-nodes per bucket
#define NCHUNK 782    // ceil(NEDGE/4096)
#define PROJB 782     // ceil(100000/128): proj1 blocks in packed mid kernel
#define SCAP 12288    // sortB staged capacity (48KB); max bucket ~8.5K

typedef int v4i __attribute__((ext_vector_type(4)));
typedef __attribute__((ext_vector_type(8))) short bf16x8;
typedef __attribute__((ext_vector_type(4))) float f32x4;

// f32 -> bf16 (RNE)
__device__ __forceinline__ unsigned short f2b(float f) {
  union { float f; unsigned u; } v;
  v.f = f;
  unsigned r = v.u + 0x7FFFu + ((v.u >> 16) & 1u);
  return (unsigned short)(r >> 16);
}

// accumulate 8 bf16 (one uint4 = 16B) into 8 fp32
__device__ __forceinline__ void accum8(uint4 w, float* a) {
  union { unsigned u; float f; } t;
  t.u = w.x << 16;         a[0] += t.f;
  t.u = w.x & 0xFFFF0000u; a[1] += t.f;
  t.u = w.y << 16;         a[2] += t.f;
  t.u = w.y & 0xFFFF0000u; a[3] += t.f;
  t.u = w.z << 16;         a[4] += t.f;
  t.u = w.z & 0xFFFF0000u; a[5] += t.f;
  t.u = w.w << 16;         a[6] += t.f;
  t.u = w.w & 0xFFFF0000u; a[7] += t.f;
}

// R14: 16-lane-per-node CSR gather (d = 16B half, p in [0,8) edge interleave).
// Avg 32-edge row = 8 chunks -> exactly 1 chunk/lane: min serial depth, 2x TLP
// vs the 8-lane version. Coverage: head [beg,bA) by p0, tail [eA,end) by p7,
// main processes j..j+3 & j+32..j+35 step 64, cleanup j..j+3 step 32
// (enumerated over (eA-bA) in {0,4,...,68}: every edge exactly once).
__device__ __forceinline__ void gather_node16(
    const int* __restrict__ rowptr, const int* __restrict__ colsrc,
    const uint4* __restrict__ valb8, int n, int d, int p, float* a) {
  int beg = rowptr[n], end = rowptr[n + 1];
#pragma unroll
  for (int k = 0; k < 8; ++k) a[k] = 0.f;
  int bA = (beg + 3) & ~3;
  int eA = end & ~3;
  if (bA > eA) {
    if (p == 0)
      for (int j = beg; j < end; ++j) accum8(valb8[colsrc[j] * 2 + d], a);
  } else {
    if (p == 0) {
      for (int j = beg; j < bA; ++j) accum8(valb8[colsrc[j] * 2 + d], a);
    } else if (p == 7) {
      for (int j = eA; j < end; ++j) accum8(valb8[colsrc[j] * 2 + d], a);
    }
    float a1[8] = {0.f, 0.f, 0.f, 0.f, 0.f, 0.f, 0.f, 0.f};
    int j = bA + p * 4;
    for (; j + 36 <= eA; j += 64) {
      v4i c0 = __builtin_nontemporal_load((const v4i*)(colsrc + j));
      v4i c1 = __builtin_nontemporal_load((const v4i*)(colsrc + j + 32));
      uint4 w0 = valb8[c0.x * 2 + d];
      uint4 w1 = valb8[c0.y * 2 + d];
      uint4 w2 = valb8[c0.z * 2 + d];
      uint4 w3 = valb8[c0.w * 2 + d];
      uint4 w4 = valb8[c1.x * 2 + d];
      uint4 w5 = valb8[c1.y * 2 + d];
      uint4 w6 = valb8[c1.z * 2 + d];
      uint4 w7 = valb8[c1.w * 2 + d];
      accum8(w0, a);
      accum8(w1, a1);
      accum8(w2, a);
      accum8(w3, a1);
      accum8(w4, a);
      accum8(w5, a1);
      accum8(w6, a);
      accum8(w7, a1);
    }
    for (; j + 4 <= eA; j += 32) {
      v4i c0 = __builtin_nontemporal_load((const v4i*)(colsrc + j));
      accum8(valb8[c0.x * 2 + d], a);
      accum8(valb8[c0.y * 2 + d], a1);
      accum8(valb8[c0.z * 2 + d], a);
      accum8(valb8[c0.w * 2 + d], a1);
    }
#pragma unroll
    for (int k = 0; k < 8; ++k) a[k] += a1[k];
  }
  // reduce over the 8 p-lanes (tid bits 1..3)
#pragma unroll
  for (int k = 0; k < 8; ++k) {
    a[k] += __shfl_xor(a[k], 2);
    a[k] += __shfl_xor(a[k], 4);
    a[k] += __shfl_xor(a[k], 8);
  }
}

// ---------------------------------------------------------------------------
// histB: bucket histogram, LDS pre-aggregation, int4-vectorized dst reads.
// ---------------------------------------------------------------------------
__global__ __launch_bounds__(512) void histB_kernel(
    const int* __restrict__ dst, int* __restrict__ bcnt) {
  __shared__ int hc[NBUCK];
  for (int t = threadIdx.x; t < NBUCK; t += 512) hc[t] = 0;
  __syncthreads();
  int e0 = blockIdx.x * 4096 + threadIdx.x * 8;
  if (e0 + 8 <= NEDGE) {
    int4 a = *(const int4*)(dst + e0);
    int4 b = *(const int4*)(dst + e0 + 4);
    atomicAdd(&hc[a.x >> 8], 1);
    atomicAdd(&hc[a.y >> 8], 1);
    atomicAdd(&hc[a.z >> 8], 1);
    atomicAdd(&hc[a.w >> 8], 1);
    atomicAdd(&hc[b.x >> 8], 1);
    atomicAdd(&hc[b.y >> 8], 1);
    atomicAdd(&hc[b.z >> 8], 1);
    atomicAdd(&hc[b.w >> 8], 1);
  } else {
    for (int e = e0; e < NEDGE; ++e) atomicAdd(&hc[dst[e] >> 8], 1);
  }
  __syncthreads();
  for (int t = threadIdx.x; t < NBUCK; t += 512) {
    int v = hc[t];
    if (v) atomicAdd(&bcnt[t], v);
  }
}

// ---------------------------------------------------------------------------
// scan: exclusive scan of 391 counts -> boff, gcursor; set sentinels.
// ---------------------------------------------------------------------------
__global__ __launch_bounds__(512) void scan_kernel(
    const int* __restrict__ bcnt, int* __restrict__ boff,
    int* __restrict__ gcursor, int* __restrict__ rowptr) {
  __shared__ int s[512];
  int v = (threadIdx.x < NBUCK) ? bcnt[threadIdx.x] : 0;
  s[threadIdx.x] = v;
  __syncthreads();
  for (int off = 1; off < 512; off <<= 1) {
    int t = (threadIdx.x >= off) ? s[threadIdx.x - off] : 0;
    __syncthreads();
    s[threadIdx.x] += t;
    __syncthreads();
  }
  if (threadIdx.x < NBUCK) {
    int e = s[threadIdx.x] - v;
    boff[threadIdx.x] = e;
    gcursor[threadIdx.x] = e;
  }
  if (threadIdx.x == 0) {
    boff[NBUCK] = NEDGE;
    rowptr[N_NODES] = NEDGE;
  }
}

// ---------------------------------------------------------------------------
// mid: PACKED partA || proj1 (R11, measured good 44.3us).
// blocks [0,NCHUNK): partA (LDS write staging).
// blocks [NCHUNK,NCHUNK+PROJB): proj1 MFMA, 128 nodes/block.
// ---------------------------------------------------------------------------
__global__ __launch_bounds__(512) void mid_kernel(
    const int* __restrict__ src, const int* __restrict__ dst,
    int* __restrict__ gcursor, unsigned* __restrict__ recs,
    const float* __restrict__ x, const float* __restrict__ W1,
    const float* __restrict__ root1,
    unsigned* __restrict__ xw1b, float* __restrict__ xr1) {
  __shared__ __attribute__((aligned(16))) char smem[31328];
  int tid = threadIdx.x;

  if (blockIdx.x < NCHUNK) {
    // ---- partA ----
    int* cnt = (int*)smem;
    int* start = (int*)(smem + 1568);
    int* base = (int*)(smem + 3136);
    int* scn = (int*)(smem + 4704);
    unsigned* srec = (unsigned*)(smem + 6752);
    unsigned short* sbk = (unsigned short*)(smem + 23136);

    for (int t = tid; t < NBUCK; t += 512) cnt[t] = 0;
    __syncthreads();

    int ebase = blockIdx.x * 4096;
    int nblk = NEDGE - ebase;
    if (nblk > 4096) nblk = 4096;

    unsigned recv[8];
    int bk[8];
    int rank[8];
    int e0 = ebase + tid * 8;
    if (e0 + 8 <= NEDGE) {
      int4 d0 = *(const int4*)(dst + e0);
      int4 d1 = *(const int4*)(dst + e0 + 4);
      int4 s0 = *(const int4*)(src + e0);
      int4 s1 = *(const int4*)(src + e0 + 4);
      int dv[8] = {d0.x, d0.y, d0.z, d0.w, d1.x, d1.y, d1.z, d1.w};
      int sv[8] = {s0.x, s0.y, s0.z, s0.w, s1.x, s1.y, s1.z, s1.w};
#pragma unroll
      for (int k = 0; k < 8; ++k) {
        bk[k] = dv[k] >> 8;
        recv[k] = (unsigned)sv[k] | ((unsigned)(dv[k] & 255) << 17);
        rank[k] = atomicAdd(&cnt[bk[k]], 1);
      }
    } else {
#pragma unroll
      for (int k = 0; k < 8; ++k) {
        int e = e0 + k;
        if (e < NEDGE) {
          int d = dst[e];
          bk[k] = d >> 8;
          recv[k] = (unsigned)src[e] | ((unsigned)(d & 255) << 17);
          rank[k] = atomicAdd(&cnt[bk[k]], 1);
        } else {
          bk[k] = -1;
        }
      }
    }
    __syncthreads();

    int v = (tid < NBUCK) ? cnt[tid] : 0;
    scn[tid] = v;
    __syncthreads();
    for (int off = 1; off < 512; off <<= 1) {
      int t = (tid >= off) ? scn[tid - off] : 0;
      __syncthreads();
      scn[tid] += t;
      __syncthreads();
    }
    if (tid < NBUCK) {
      start[tid] = scn[tid] - v;
      base[tid] = v ? atomicAdd(&gcursor[tid], v) : 0;
    }
    __syncthreads();

#pragma unroll
    for (int k = 0; k < 8; ++k) {
      if (bk[k] >= 0) {
        int pos = start[bk[k]] + rank[k];
        srec[pos] = recv[k];
        sbk[pos] = (unsigned short)bk[k];
      }
    }
    __syncthreads();

    for (int i = tid; i < nblk; i += 512) {
      int b = sbk[i];
      recs[base[b] + (i - start[b])] = srec[i];
    }
  } else {
    // ---- proj1 (MFMA) ----
    unsigned short* Wb = (unsigned short*)smem;  // [2][4][4][16][8]
    for (int t = tid; t < 4096; t += 512) {
      int cgx = t >> 11;
      int rem = t & 2047;
      int kb = rem >> 9;
      int g = (rem >> 7) & 3;
      int c = (rem >> 3) & 15;
      int i = rem & 7;
      int k = kb * 32 + g * 8 + i;
      float v = (cgx == 0) ? W1[FIN * HID + k * HID + c] : root1[k * HID + c];
      Wb[((((cgx * 4 + kb) * 4 + g) * 16) + c) * 8 + i] = f2b(v);
    }
    __syncthreads();

    int wid = tid >> 6;
    int lane = tid & 63;
    int n0 = (blockIdx.x - NCHUNK) * 128 + wid * 16;
    if (n0 >= N_NODES) return;  // wave-uniform

    int row = lane & 15;
    int g = lane >> 4;
    const float* xp = x + (size_t)(n0 + row) * FIN + g * 8;

    bf16x8 afr[4];
#pragma unroll
    for (int kb = 0; kb < 4; ++kb) {
      float4 u0 = *(const float4*)(xp + kb * 32);
      float4 u1 = *(const float4*)(xp + kb * 32 + 4);
      bf16x8 a;
      a[0] = (short)f2b(u0.x);
      a[1] = (short)f2b(u0.y);
      a[2] = (short)f2b(u0.z);
      a[3] = (short)f2b(u0.w);
      a[4] = (short)f2b(u1.x);
      a[5] = (short)f2b(u1.y);
      a[6] = (short)f2b(u1.z);
      a[7] = (short)f2b(u1.w);
      afr[kb] = a;
    }

    f32x4 c0 = {0.f, 0.f, 0.f, 0.f};
    f32x4 c1 = {0.f, 0.f, 0.f, 0.f};
#pragma unroll
    for (int kb = 0; kb < 4; ++kb) {
      bf16x8 b0 = *(const bf16x8*)&Wb[(((0 * 4 + kb) * 4 + g) * 16 + row) * 8];
      c0 = __builtin_amdgcn_mfma_f32_16x16x32_bf16(afr[kb], b0, c0, 0, 0, 0);
    }
#pragma unroll
    for (int kb = 0; kb < 4; ++kb) {
      bf16x8 b1 = *(const bf16x8*)&Wb[(((1 * 4 + kb) * 4 + g) * 16 + row) * 8];
      c1 = __builtin_amdgcn_mfma_f32_16x16x32_bf16(afr[kb], b1, c1, 0, 0, 0);
    }

    int col = lane & 15;
    unsigned short* xwu = (unsigned short*)xw1b;
#pragma unroll
    for (int r = 0; r < 4; ++r) {
      int n = n0 + g * 4 + r;
      xwu[(size_t)n * HID + col] = f2b(c0[r]);
      xr1[(size_t)n * HID + col] = c1[r];
    }
  }
}

// ---------------------------------------------------------------------------
// sortB: per-bucket counting sort with LDS staged output (measured good).
// ---------------------------------------------------------------------------
__global__ __launch_bounds__(1024) void sortB_kernel(
    const int* __restrict__ boff, const unsigned* __restrict__ recs,
    int* __restrict__ rowptr, int* __restrict__ colsrc) {
  __shared__ int hist[256];
  __shared__ int s[256];
  __shared__ int cur[256];
  __shared__ int staged[SCAP];  // 48KB
  if (threadIdx.x < 256) hist[threadIdx.x] = 0;
  __syncthreads();

  int b = blockIdx.x;
  int beg = boff[b], end = boff[b + 1];
  for (int j = beg + threadIdx.x; j < end; j += 1024)
    atomicAdd(&hist[recs[j] >> 17], 1);
  __syncthreads();

  if (threadIdx.x < 256) s[threadIdx.x] = hist[threadIdx.x];
  __syncthreads();
  for (int off = 1; off < 256; off <<= 1) {
    int t = 0;
    if (threadIdx.x < 256 && threadIdx.x >= off) t = s[threadIdx.x - off];
    __syncthreads();
    if (threadIdx.x < 256) s[threadIdx.x] += t;
    __syncthreads();
  }
  if (threadIdx.x < 256) {
    int excl = s[threadIdx.x] - hist[threadIdx.x];
    int n = b * 256 + threadIdx.x;
    if (n < N_NODES) rowptr[n] = beg + excl;
    cur[threadIdx.x] = excl;
  }
  __syncthreads();

  for (int j = beg + threadIdx.x; j < end; j += 1024) {
    unsigned r = recs[j];
    int dl = r >> 17;
    int pos = atomicAdd(&cur[dl], 1);
    if (pos < SCAP) staged[pos] = (int)(r & 0x1FFFF);
    else colsrc[beg + pos] = (int)(r & 0x1FFFF);  // overflow fallback (rare)
  }
  __syncthreads();

  int size = end - beg;
  if (size > SCAP) size = SCAP;
  for (int i = threadIdx.x; i < size; i += 1024) colsrc[beg + i] = staged[i];
}

// ---------------------------------------------------------------------------
// R14 gather1: 16 lanes/node (doubled TLP vs R11's 8). fp32 accum; fused
// mean+xr1+b1+ELU -> hb (bf16 table). Grid exact: 6250*256 = 100000*16.
// ---------------------------------------------------------------------------
__global__ __launch_bounds__(256) void gather1_kernel(
    const int* __restrict__ rowptr, const int* __restrict__ colsrc,
    const uint4* __restrict__ valb8, const float4* __restrict__ xr14,
    const float* __restrict__ b1, uint4* __restrict__ hb8) {
  int t = blockIdx.x * 256 + threadIdx.x;
  int n = t >> 4;
  if (n >= N_NODES) return;
  int d = t & 1;
  int p = (t >> 1) & 7;

  float a[8];
  gather_node16(rowptr, colsrc, valb8, n, d, p, a);
  if (p) return;

  int beg = rowptr[n], end = rowptr[n + 1];
  float inv = 1.0f / fmaxf((float)(end - beg), 1.0f);
  float4 r0 = xr14[n * 4 + 2 * d];
  float4 r1 = xr14[n * 4 + 2 * d + 1];
  const float4* bb = (const float4*)b1;
  float4 bb0 = bb[2 * d], bb1 = bb[2 * d + 1];
  float o[8];
  o[0] = a[0] * inv + r0.x + bb0.x;
  o[1] = a[1] * inv + r0.y + bb0.y;
  o[2] = a[2] * inv + r0.z + bb0.z;
  o[3] = a[3] * inv + r0.w + bb0.w;
  o[4] = a[4] * inv + r1.x + bb1.x;
  o[5] = a[5] * inv + r1.y + bb1.y;
  o[6] = a[6] * inv + r1.z + bb1.z;
  o[7] = a[7] * inv + r1.w + bb1.w;
#pragma unroll
  for (int k = 0; k < 8; ++k) o[k] = (o[k] > 0.f) ? o[k] : expm1f(o[k]);
  uint4 pk;
  pk.x = (unsigned)f2b(o[0]) | ((unsigned)f2b(o[1]) << 16);
  pk.y = (unsigned)f2b(o[2]) | ((unsigned)f2b(o[3]) << 16);
  pk.z = (unsigned)f2b(o[4]) | ((unsigned)f2b(o[5]) << 16);
  pk.w = (unsigned)f2b(o[6]) | ((unsigned)f2b(o[7]) << 16);
  hb8[n * 2 + d] = pk;
}

// ---------------------------------------------------------------------------
// R14 g2out: FUSED gather2 + out, 16 lanes/node (16 nodes per 256-thr block).
// Gather -> aggl (LDS); out phase 16 thr/node with class-split duplicated
// across bit3 (identical-value double stores, benign). Grid exact: 6250.
// ---------------------------------------------------------------------------
__global__ __launch_bounds__(256) void g2out_kernel(
    const int* __restrict__ rowptr, const int* __restrict__ colsrc,
    const uint4* __restrict__ valb8, const unsigned* __restrict__ hbu,
    const float* __restrict__ W2, const float* __restrict__ root2,
    const float* __restrict__ b2v, float* __restrict__ out) {
  __shared__ float aggl[16][17];
  __shared__ float hl[16][17];
  __shared__ float Wl[HID * NCLS];
  __shared__ float Rl[HID * NCLS];
  __shared__ float Bl[NCLS];

  int tid = threadIdx.x;
  for (int i = tid; i < HID * NCLS; i += 256) {
    Wl[i] = W2[HID * NCLS + i];
    Rl[i] = root2[i];
  }
  if (tid < NCLS) Bl[tid] = b2v[tid];
  {
    // stage this block's 16 hb rows (bf16->fp32): 128 uints = 256 values
    if (tid < 128) {
      unsigned u = hbu[(size_t)blockIdx.x * 128 + tid];
      union { unsigned u; float f; } lo, hi;
      lo.u = u << 16;
      hi.u = u & 0xFFFF0000u;
      int nl = tid >> 3, uu = tid & 7;
      hl[nl][uu * 2] = lo.f;
      hl[nl][uu * 2 + 1] = hi.f;
    }
  }

  // ---- gather phase ----
  int nl = tid >> 4;
  int n = blockIdx.x * 16 + nl;
  int d = tid & 1;
  int p = (tid >> 1) & 7;

  float a[8];
  gather_node16(rowptr, colsrc, valb8, n, d, p, a);
  if (p == 0) {
    int beg = rowptr[n], end = rowptr[n + 1];
    float inv = 1.0f / fmaxf((float)(end - beg), 1.0f);
#pragma unroll
    for (int k = 0; k < 8; ++k) aggl[nl][d * 8 + k] = a[k] * inv;
  }
  __syncthreads();

  // ---- out phase: 8-class-split q = tid&7, duplicated across bit3 ----
  int q = tid & 7;
  float lg[5];
#pragma unroll
  for (int jj = 0; jj < 5; ++jj) lg[jj] = Bl[q * 5 + jj];
  for (int c = 0; c < HID; ++c) {
    float ac = aggl[nl][c];
    float hc = hl[nl][c];
    const float* wrow = Wl + c * NCLS + q * 5;
    const float* rrow = Rl + c * NCLS + q * 5;
#pragma unroll
    for (int jj = 0; jj < 5; ++jj) lg[jj] += ac * wrow[jj] + hc * rrow[jj];
  }
  float m = lg[0];
#pragma unroll
  for (int jj = 1; jj < 5; ++jj) m = fmaxf(m, lg[jj]);
  m = fmaxf(m, __shfl_xor(m, 1));
  m = fmaxf(m, __shfl_xor(m, 2));
  m = fmaxf(m, __shfl_xor(m, 4));
  float s = 0.f;
#pragma unroll
  for (int jj = 0; jj < 5; ++jj) s += expf(lg[jj] - m);
  s += __shfl_xor(s, 1);
  s += __shfl_xor(s, 2);
  s += __shfl_xor(s, 4);
  float lse = m + logf(s);
  float* op = out + (size_t)n * NCLS + q * 5;
#pragma unroll
  for (int jj = 0; jj < 5; ++jj) op[jj] = lg[jj] - lse;
}

extern "C" void kernel_launch(void* const* d_in, const int* in_sizes, int n_in,
                              void* d_out, int out_size, void* d_ws,
                              size_t ws_size, hipStream_t stream) {
  const float* x = (const float*)d_in[0];
  const int* ei = (const int*)d_in[1];  // (2, E): src row then dst row
  const float* W1 = (const float*)d_in[2];
  const float* root1 = (const float*)d_in[3];
  const float* b1 = (const float*)d_in[4];
  const float* W2 = (const float*)d_in[5];
  const float* root2 = (const float*)d_in[6];
  const float* b2v = (const float*)d_in[7];
  float* out = (float*)d_out;

  const int* src = ei;
  const int* dstp = ei + NEDGE;

  // workspace (bytes):
  // [bcnt 2K][boff 2K][gcursor 2K][rowptr (N+4)*4][recs E*4][colsrc E*4]
  // [xw1b 16N*2][xr1 16N*4][hb 16N*2]
  char* w = (char*)d_ws;
  int* bcnt = (int*)w;           w += 2048;
  int* boff = (int*)w;           w += 2048;
  int* gcursor = (int*)w;        w += 2048;
  int* rowptr = (int*)w;         w += (size_t)(N_NODES + 4) * 4;
  unsigned* recs = (unsigned*)w; w += (size_t)NEDGE * 4;
  int* colsrc = (int*)w;         w += (size_t)NEDGE * 4;
  unsigned* xw1b = (unsigned*)w; w += (size_t)N_NODES * HID * 2;
  float* xr1 = (float*)w;        w += (size_t)N_NODES * HID * 4;
  unsigned* hbu = (unsigned*)w;  w += (size_t)N_NODES * HID * 2;

  hipMemsetAsync(bcnt, 0, 2048, stream);

  histB_kernel<<<NCHUNK, 512, 0, stream>>>(dstp, bcnt);
  scan_kernel<<<1, 512, 0, stream>>>(bcnt, boff, gcursor, rowptr);
  mid_kernel<<<NCHUNK + PROJB, 512, 0, stream>>>(src, dstp, gcursor, recs, x,
                                                 W1, root1, xw1b, xr1);
  sortB_kernel<<<NBUCK, 1024, 0, stream>>>(boff, recs, rowptr, colsrc);
  gather1_kernel<<<(N_NODES * 16 + 255) / 256, 256, 0, stream>>>(
      rowptr, colsrc, (const uint4*)xw1b, (const float4*)xr1, b1,
      (uint4*)hbu);
  g2out_kernel<<<(N_NODES + 15) / 16, 256, 0, stream>>>(
      rowptr, colsrc, (const uint4*)hbu, hbu, W2, root2, b2v, out);
}

// Round 15
// 239.514 us; speedup vs baseline: 1.1043x; 1.1043x over previous
//
#include <hip/hip_runtime.h>
#include <hip/hip_bf16.h>

#define N_NODES 100000
#define FIN 128
#define HID 16
#define NCLS 40
#define NEDGE 3200000
#define NBUCK 391     // ceil(100000/256): 256 dst-nodes per bucket
#define NCHUNK 782    // ceil(NEDGE/4096)
#define PROJB 782     // ceil(100000/128): proj1 blocks in packed mid kernel
#define SCAP 12288    // sortB staged capacity (48KB); max bucket ~8.5K

typedef int v4i __attribute__((ext_vector_type(4)));
typedef __attribute__((ext_vector_type(8))) short bf16x8;
typedef __attribute__((ext_vector_type(4))) float f32x4;

// f32 -> bf16 (RNE)
__device__ __forceinline__ unsigned short f2b(float f) {
  union { float f; unsigned u; } v;
  v.f = f;
  unsigned r = v.u + 0x7FFFu + ((v.u >> 16) & 1u);
  return (unsigned short)(r >> 16);
}

// accumulate 8 bf16 (one uint4 = 16B) into 8 fp32
__device__ __forceinline__ void accum8(uint4 w, float* a) {
  union { unsigned u; float f; } t;
  t.u = w.x << 16;         a[0] += t.f;
  t.u = w.x & 0xFFFF0000u; a[1] += t.f;
  t.u = w.y << 16;         a[2] += t.f;
  t.u = w.y & 0xFFFF0000u; a[3] += t.f;
  t.u = w.z << 16;         a[4] += t.f;
  t.u = w.z & 0xFFFF0000u; a[5] += t.f;
  t.u = w.w << 16;         a[6] += t.f;
  t.u = w.w & 0xFFFF0000u; a[7] += t.f;
}

// ---------------------------------------------------------------------------
// histB: bucket histogram, LDS pre-aggregation, int4-vectorized dst reads.
// ---------------------------------------------------------------------------
__global__ __launch_bounds__(512) void histB_kernel(
    const int* __restrict__ dst, int* __restrict__ bcnt) {
  __shared__ int hc[NBUCK];
  for (int t = threadIdx.x; t < NBUCK; t += 512) hc[t] = 0;
  __syncthreads();
  int e0 = blockIdx.x * 4096 + threadIdx.x * 8;
  if (e0 + 8 <= NEDGE) {
    int4 a = *(const int4*)(dst + e0);
    int4 b = *(const int4*)(dst + e0 + 4);
    atomicAdd(&hc[a.x >> 8], 1);
    atomicAdd(&hc[a.y >> 8], 1);
    atomicAdd(&hc[a.z >> 8], 1);
    atomicAdd(&hc[a.w >> 8], 1);
    atomicAdd(&hc[b.x >> 8], 1);
    atomicAdd(&hc[b.y >> 8], 1);
    atomicAdd(&hc[b.z >> 8], 1);
    atomicAdd(&hc[b.w >> 8], 1);
  } else {
    for (int e = e0; e < NEDGE; ++e) atomicAdd(&hc[dst[e] >> 8], 1);
  }
  __syncthreads();
  for (int t = threadIdx.x; t < NBUCK; t += 512) {
    int v = hc[t];
    if (v) atomicAdd(&bcnt[t], v);
  }
}

// ---------------------------------------------------------------------------
// R15 mid: PACKED partA || proj1 (R11 bodies). partA now computes the global
// boff scan LOCALLY from bcnt (histB complete before this dispatch) -> the
// scan_kernel dispatch is deleted. gcursor is zero-initialized by the memset;
// write position = boffl[b] + atomicAdd(&gcursor[b], cv).
// blocks [0,NCHUNK): partA. blocks [NCHUNK,NCHUNK+PROJB): proj1 MFMA.
// ---------------------------------------------------------------------------
__global__ __launch_bounds__(512) void mid_kernel(
    const int* __restrict__ src, const int* __restrict__ dst,
    const int* __restrict__ bcnt, int* __restrict__ gcursor,
    unsigned* __restrict__ recs,
    const float* __restrict__ x, const float* __restrict__ W1,
    const float* __restrict__ root1,
    unsigned* __restrict__ xw1b, float* __restrict__ xr1) {
  __shared__ __attribute__((aligned(16))) char smem[31328];
  int tid = threadIdx.x;

  if (blockIdx.x < NCHUNK) {
    // ---- partA ----
    int* cnt = (int*)smem;                          // 391
    int* start = (int*)(smem + 1568);               // 391
    int* base = (int*)(smem + 3136);                // 391 (holds boffl, then final base)
    int* scn = (int*)(smem + 4704);                 // 512
    unsigned* srec = (unsigned*)(smem + 6752);      // 4096 u32
    unsigned short* sbk = (unsigned short*)(smem + 23136);  // 4096 u16

    // local scan of bcnt -> base[] = global exclusive offsets (boff)
    {
      int gv = (tid < NBUCK) ? bcnt[tid] : 0;
      scn[tid] = gv;
      __syncthreads();
      for (int off = 1; off < 512; off <<= 1) {
        int t = (tid >= off) ? scn[tid - off] : 0;
        __syncthreads();
        scn[tid] += t;
        __syncthreads();
      }
      if (tid < NBUCK) base[tid] = scn[tid] - gv;
      __syncthreads();
    }

    for (int t = tid; t < NBUCK; t += 512) cnt[t] = 0;
    __syncthreads();

    int ebase = blockIdx.x * 4096;
    int nblk = NEDGE - ebase;
    if (nblk > 4096) nblk = 4096;

    unsigned recv[8];
    int bk[8];
    int rank[8];
    int e0 = ebase + tid * 8;
    if (e0 + 8 <= NEDGE) {
      int4 d0 = *(const int4*)(dst + e0);
      int4 d1 = *(const int4*)(dst + e0 + 4);
      int4 s0 = *(const int4*)(src + e0);
      int4 s1 = *(const int4*)(src + e0 + 4);
      int dv[8] = {d0.x, d0.y, d0.z, d0.w, d1.x, d1.y, d1.z, d1.w};
      int sv[8] = {s0.x, s0.y, s0.z, s0.w, s1.x, s1.y, s1.z, s1.w};
#pragma unroll
      for (int k = 0; k < 8; ++k) {
        bk[k] = dv[k] >> 8;
        recv[k] = (unsigned)sv[k] | ((unsigned)(dv[k] & 255) << 17);
        rank[k] = atomicAdd(&cnt[bk[k]], 1);
      }
    } else {
#pragma unroll
      for (int k = 0; k < 8; ++k) {
        int e = e0 + k;
        if (e < NEDGE) {
          int d = dst[e];
          bk[k] = d >> 8;
          recv[k] = (unsigned)src[e] | ((unsigned)(d & 255) << 17);
          rank[k] = atomicAdd(&cnt[bk[k]], 1);
        } else {
          bk[k] = -1;
        }
      }
    }
    __syncthreads();

    int v = (tid < NBUCK) ? cnt[tid] : 0;
    scn[tid] = v;
    __syncthreads();
    for (int off = 1; off < 512; off <<= 1) {
      int t = (tid >= off) ? scn[tid - off] : 0;
      __syncthreads();
      scn[tid] += t;
      __syncthreads();
    }
    if (tid < NBUCK) {
      start[tid] = scn[tid] - v;
      if (v) base[tid] += atomicAdd(&gcursor[tid], v);
    }
    __syncthreads();

#pragma unroll
    for (int k = 0; k < 8; ++k) {
      if (bk[k] >= 0) {
        int pos = start[bk[k]] + rank[k];
        srec[pos] = recv[k];
        sbk[pos] = (unsigned short)bk[k];
      }
    }
    __syncthreads();

    for (int i = tid; i < nblk; i += 512) {
      int b = sbk[i];
      recs[base[b] + (i - start[b])] = srec[i];
    }
  } else {
    // ---- proj1 (MFMA) ----
    unsigned short* Wb = (unsigned short*)smem;  // [2][4][4][16][8]
    for (int t = tid; t < 4096; t += 512) {
      int cgx = t >> 11;
      int rem = t & 2047;
      int kb = rem >> 9;
      int g = (rem >> 7) & 3;
      int c = (rem >> 3) & 15;
      int i = rem & 7;
      int k = kb * 32 + g * 8 + i;
      float v = (cgx == 0) ? W1[FIN * HID + k * HID + c] : root1[k * HID + c];
      Wb[((((cgx * 4 + kb) * 4 + g) * 16) + c) * 8 + i] = f2b(v);
    }
    __syncthreads();

    int wid = tid >> 6;
    int lane = tid & 63;
    int n0 = (blockIdx.x - NCHUNK) * 128 + wid * 16;
    if (n0 >= N_NODES) return;  // wave-uniform

    int row = lane & 15;
    int g = lane >> 4;
    const float* xp = x + (size_t)(n0 + row) * FIN + g * 8;

    bf16x8 afr[4];
#pragma unroll
    for (int kb = 0; kb < 4; ++kb) {
      float4 u0 = *(const float4*)(xp + kb * 32);
      float4 u1 = *(const float4*)(xp + kb * 32 + 4);
      bf16x8 a;
      a[0] = (short)f2b(u0.x);
      a[1] = (short)f2b(u0.y);
      a[2] = (short)f2b(u0.z);
      a[3] = (short)f2b(u0.w);
      a[4] = (short)f2b(u1.x);
      a[5] = (short)f2b(u1.y);
      a[6] = (short)f2b(u1.z);
      a[7] = (short)f2b(u1.w);
      afr[kb] = a;
    }

    f32x4 c0 = {0.f, 0.f, 0.f, 0.f};
    f32x4 c1 = {0.f, 0.f, 0.f, 0.f};
#pragma unroll
    for (int kb = 0; kb < 4; ++kb) {
      bf16x8 b0 = *(const bf16x8*)&Wb[(((0 * 4 + kb) * 4 + g) * 16 + row) * 8];
      c0 = __builtin_amdgcn_mfma_f32_16x16x32_bf16(afr[kb], b0, c0, 0, 0, 0);
    }
#pragma unroll
    for (int kb = 0; kb < 4; ++kb) {
      bf16x8 b1 = *(const bf16x8*)&Wb[(((1 * 4 + kb) * 4 + g) * 16 + row) * 8];
      c1 = __builtin_amdgcn_mfma_f32_16x16x32_bf16(afr[kb], b1, c1, 0, 0, 0);
    }

    int col = lane & 15;
    unsigned short* xwu = (unsigned short*)xw1b;
#pragma unroll
    for (int r = 0; r < 4; ++r) {
      int n = n0 + g * 4 + r;
      xwu[(size_t)n * HID + col] = f2b(c0[r]);
      xr1[(size_t)n * HID + col] = c1[r];
    }
  }
}

// ---------------------------------------------------------------------------
// R15 sortB: per-bucket counting sort with LDS staged output; computes its
// own beg/end by scanning bcnt locally (scan dispatch deleted). Block 0 sets
// the rowptr[N] sentinel.
// ---------------------------------------------------------------------------
__global__ __launch_bounds__(1024) void sortB_kernel(
    const int* __restrict__ bcnt, const unsigned* __restrict__ recs,
    int* __restrict__ rowptr, int* __restrict__ colsrc) {
  __shared__ int hist[256];
  __shared__ int s[256];
  __shared__ int cur[256];
  __shared__ int s2[512];
  __shared__ int staged[SCAP];  // 48KB
  int tid = threadIdx.x;
  int b = blockIdx.x;

  // local scan of bcnt: end = inclusive[b], beg = end - bcnt[b]
  if (tid < 512) s2[tid] = (tid < NBUCK) ? bcnt[tid] : 0;
  __syncthreads();
  for (int off = 1; off < 512; off <<= 1) {
    int t = 0;
    if (tid < 512 && tid >= off) t = s2[tid - off];
    __syncthreads();
    if (tid < 512) s2[tid] += t;
    __syncthreads();
  }
  int end = s2[b];
  int beg = end - bcnt[b];
  if (b == 0 && tid == 0) rowptr[N_NODES] = NEDGE;

  if (tid < 256) hist[tid] = 0;
  __syncthreads();

  for (int j = beg + tid; j < end; j += 1024)
    atomicAdd(&hist[recs[j] >> 17], 1);
  __syncthreads();

  if (tid < 256) s[tid] = hist[tid];
  __syncthreads();
  for (int off = 1; off < 256; off <<= 1) {
    int t = 0;
    if (tid < 256 && tid >= off) t = s[tid - off];
    __syncthreads();
    if (tid < 256) s[tid] += t;
    __syncthreads();
  }
  if (tid < 256) {
    int excl = s[tid] - hist[tid];
    int n = b * 256 + tid;
    if (n < N_NODES) rowptr[n] = beg + excl;
    cur[tid] = excl;
  }
  __syncthreads();

  for (int j = beg + tid; j < end; j += 1024) {
    unsigned r = recs[j];
    int dl = r >> 17;
    int pos = atomicAdd(&cur[dl], 1);
    if (pos < SCAP) staged[pos] = (int)(r & 0x1FFFF);
    else colsrc[beg + pos] = (int)(r & 0x1FFFF);  // overflow fallback (rare)
  }
  __syncthreads();

  int size = end - beg;
  if (size > SCAP) size = SCAP;
  for (int i = tid; i < size; i += 1024) colsrc[beg + i] = staged[i];
}

// ---------------------------------------------------------------------------
// gather1 (R11 8-lane version, measured good): 16B requests, fp32 accum,
// fused mean+xr1+b1+ELU -> hb (bf16 table).
// ---------------------------------------------------------------------------
__global__ __launch_bounds__(256) void gather1_kernel(
    const int* __restrict__ rowptr, const int* __restrict__ colsrc,
    const uint4* __restrict__ valb8, const float4* __restrict__ xr14,
    const float* __restrict__ b1, uint4* __restrict__ hb8) {
  int t = blockIdx.x * 256 + threadIdx.x;
  int n = t >> 3;
  if (n >= N_NODES) return;
  int d = t & 1;
  int p = (t >> 1) & 3;
  int beg = rowptr[n], end = rowptr[n + 1];

  float a[8] = {0.f, 0.f, 0.f, 0.f, 0.f, 0.f, 0.f, 0.f};
  int bA = (beg + 3) & ~3;
  int eA = end & ~3;
  if (bA > eA) {
    if (p == 0)
      for (int j = beg; j < end; ++j) accum8(valb8[colsrc[j] * 2 + d], a);
  } else {
    if (p == 0) {
      for (int j = beg; j < bA; ++j) accum8(valb8[colsrc[j] * 2 + d], a);
    } else if (p == 3) {
      for (int j = eA; j < end; ++j) accum8(valb8[colsrc[j] * 2 + d], a);
    }
    float a1[8] = {0.f, 0.f, 0.f, 0.f, 0.f, 0.f, 0.f, 0.f};
    int j = bA + p * 4;
    for (; j + 20 <= eA; j += 32) {
      v4i c0 = __builtin_nontemporal_load((const v4i*)(colsrc + j));
      v4i c1 = __builtin_nontemporal_load((const v4i*)(colsrc + j + 16));
      uint4 w0 = valb8[c0.x * 2 + d];
      uint4 w1 = valb8[c0.y * 2 + d];
      uint4 w2 = valb8[c0.z * 2 + d];
      uint4 w3 = valb8[c0.w * 2 + d];
      uint4 w4 = valb8[c1.x * 2 + d];
      uint4 w5 = valb8[c1.y * 2 + d];
      uint4 w6 = valb8[c1.z * 2 + d];
      uint4 w7 = valb8[c1.w * 2 + d];
      accum8(w0, a);
      accum8(w1, a1);
      accum8(w2, a);
      accum8(w3, a1);
      accum8(w4, a);
      accum8(w5, a1);
      accum8(w6, a);
      accum8(w7, a1);
    }
    for (; j + 4 <= eA; j += 16) {
      v4i c0 = __builtin_nontemporal_load((const v4i*)(colsrc + j));
      accum8(valb8[c0.x * 2 + d], a);
      accum8(valb8[c0.y * 2 + d], a1);
      accum8(valb8[c0.z * 2 + d], a);
      accum8(valb8[c0.w * 2 + d], a1);
    }
#pragma unroll
    for (int k = 0; k < 8; ++k) a[k] += a1[k];
  }

#pragma unroll
  for (int k = 0; k < 8; ++k) {
    a[k] += __shfl_xor(a[k], 2);
    a[k] += __shfl_xor(a[k], 4);
  }
  if (p) return;

  float inv = 1.0f / fmaxf((float)(end - beg), 1.0f);
  float4 r0 = xr14[n * 4 + 2 * d];
  float4 r1 = xr14[n * 4 + 2 * d + 1];
  const float4* bb = (const float4*)b1;
  float4 bb0 = bb[2 * d], bb1 = bb[2 * d + 1];
  float o[8];
  o[0] = a[0] * inv + r0.x + bb0.x;
  o[1] = a[1] * inv + r0.y + bb0.y;
  o[2] = a[2] * inv + r0.z + bb0.z;
  o[3] = a[3] * inv + r0.w + bb0.w;
  o[4] = a[4] * inv + r1.x + bb1.x;
  o[5] = a[5] * inv + r1.y + bb1.y;
  o[6] = a[6] * inv + r1.z + bb1.z;
  o[7] = a[7] * inv + r1.w + bb1.w;
#pragma unroll
  for (int k = 0; k < 8; ++k) o[k] = (o[k] > 0.f) ? o[k] : expm1f(o[k]);
  uint4 pk;
  pk.x = (unsigned)f2b(o[0]) | ((unsigned)f2b(o[1]) << 16);
  pk.y = (unsigned)f2b(o[2]) | ((unsigned)f2b(o[3]) << 16);
  pk.z = (unsigned)f2b(o[4]) | ((unsigned)f2b(o[5]) << 16);
  pk.w = (unsigned)f2b(o[6]) | ((unsigned)f2b(o[7]) << 16);
  hb8[n * 2 + d] = pk;
}

// ---------------------------------------------------------------------------
// g2out (R11 version, measured good): FUSED gather2 + out. 32 nodes/block,
// 8 lanes/node; agg in LDS; logits + log_softmax; h read from hb (bf16).
// ---------------------------------------------------------------------------
__global__ __launch_bounds__(256) void g2out_kernel(
    const int* __restrict__ rowptr, const int* __restrict__ colsrc,
    const uint4* __restrict__ valb8, const unsigned* __restrict__ hbu,
    const float* __restrict__ W2, const float* __restrict__ root2,
    const float* __restrict__ b2v, float* __restrict__ out) {
  __shared__ float aggl[32][17];
  __shared__ float hl[32][17];
  __shared__ float Wl[HID * NCLS];
  __shared__ float Rl[HID * NCLS];
  __shared__ float Bl[NCLS];

  int tid = threadIdx.x;
  for (int i = tid; i < HID * NCLS; i += 256) {
    Wl[i] = W2[HID * NCLS + i];
    Rl[i] = root2[i];
  }
  if (tid < NCLS) Bl[tid] = b2v[tid];
  {
    unsigned u = hbu[(size_t)blockIdx.x * 256 + tid];
    union { unsigned u; float f; } lo, hi;
    lo.u = u << 16;
    hi.u = u & 0xFFFF0000u;
    int nl = tid >> 3, uu = tid & 7;
    hl[nl][uu * 2] = lo.f;
    hl[nl][uu * 2 + 1] = hi.f;
  }

  int nl = tid >> 3;
  int n = blockIdx.x * 32 + nl;
  int d = tid & 1;
  int p = (tid >> 1) & 3;
  int beg = rowptr[n], end = rowptr[n + 1];

  float a[8] = {0.f, 0.f, 0.f, 0.f, 0.f, 0.f, 0.f, 0.f};
  int bA = (beg + 3) & ~3;
  int eA = end & ~3;
  if (bA > eA) {
    if (p == 0)
      for (int j = beg; j < end; ++j) accum8(valb8[colsrc[j] * 2 + d], a);
  } else {
    if (p == 0) {
      for (int j = beg; j < bA; ++j) accum8(valb8[colsrc[j] * 2 + d], a);
    } else if (p == 3) {
      for (int j = eA; j < end; ++j) accum8(valb8[colsrc[j] * 2 + d], a);
    }
    float a1[8] = {0.f, 0.f, 0.f, 0.f, 0.f, 0.f, 0.f, 0.f};
    int j = bA + p * 4;
    for (; j + 20 <= eA; j += 32) {
      v4i c0 = __builtin_nontemporal_load((const v4i*)(colsrc + j));
      v4i c1 = __builtin_nontemporal_load((const v4i*)(colsrc + j + 16));
      uint4 w0 = valb8[c0.x * 2 + d];
      uint4 w1 = valb8[c0.y * 2 + d];
      uint4 w2 = valb8[c0.z * 2 + d];
      uint4 w3 = valb8[c0.w * 2 + d];
      uint4 w4 = valb8[c1.x * 2 + d];
      uint4 w5 = valb8[c1.y * 2 + d];
      uint4 w6 = valb8[c1.z * 2 + d];
      uint4 w7 = valb8[c1.w * 2 + d];
      accum8(w0, a);
      accum8(w1, a1);
      accum8(w2, a);
      accum8(w3, a1);
      accum8(w4, a);
      accum8(w5, a1);
      accum8(w6, a);
      accum8(w7, a1);
    }
    for (; j + 4 <= eA; j += 16) {
      v4i c0 = __builtin_nontemporal_load((const v4i*)(colsrc + j));
      accum8(valb8[c0.x * 2 + d], a);
      accum8(valb8[c0.y * 2 + d], a1);
      accum8(valb8[c0.z * 2 + d], a);
      accum8(valb8[c0.w * 2 + d], a1);
    }
#pragma unroll
    for (int k = 0; k < 8; ++k) a[k] += a1[k];
  }

#pragma unroll
  for (int k = 0; k < 8; ++k) {
    a[k] += __shfl_xor(a[k], 2);
    a[k] += __shfl_xor(a[k], 4);
  }
  if (p == 0) {
    float inv = 1.0f / fmaxf((float)(end - beg), 1.0f);
#pragma unroll
    for (int k = 0; k < 8; ++k) aggl[nl][d * 8 + k] = a[k] * inv;
  }
  __syncthreads();

  int q = tid & 7;
  float lg[5];
#pragma unroll
  for (int jj = 0; jj < 5; ++jj) lg[jj] = Bl[q * 5 + jj];
  for (int c = 0; c < HID; ++c) {
    float ac = aggl[nl][c];
    float hc = hl[nl][c];
    const float* wrow = Wl + c * NCLS + q * 5;
    const float* rrow = Rl + c * NCLS + q * 5;
#pragma unroll
    for (int jj = 0; jj < 5; ++jj) lg[jj] += ac * wrow[jj] + hc * rrow[jj];
  }
  float m = lg[0];
#pragma unroll
  for (int jj = 1; jj < 5; ++jj) m = fmaxf(m, lg[jj]);
  m = fmaxf(m, __shfl_xor(m, 1));
  m = fmaxf(m, __shfl_xor(m, 2));
  m = fmaxf(m, __shfl_xor(m, 4));
  float s = 0.f;
#pragma unroll
  for (int jj = 0; jj < 5; ++jj) s += expf(lg[jj] - m);
  s += __shfl_xor(s, 1);
  s += __shfl_xor(s, 2);
  s += __shfl_xor(s, 4);
  float lse = m + logf(s);
  float* op = out + (size_t)n * NCLS + q * 5;
#pragma unroll
  for (int jj = 0; jj < 5; ++jj) op[jj] = lg[jj] - lse;
}

extern "C" void kernel_launch(void* const* d_in, const int* in_sizes, int n_in,
                              void* d_out, int out_size, void* d_ws,
                              size_t ws_size, hipStream_t stream) {
  const float* x = (const float*)d_in[0];
  const int* ei = (const int*)d_in[1];  // (2, E): src row then dst row
  const float* W1 = (const float*)d_in[2];
  const float* root1 = (const float*)d_in[3];
  const float* b1 = (const float*)d_in[4];
  const float* W2 = (const float*)d_in[5];
  const float* root2 = (const float*)d_in[6];
  const float* b2v = (const float*)d_in[7];
  float* out = (float*)d_out;

  const int* src = ei;
  const int* dstp = ei + NEDGE;

  // workspace (bytes):
  // [bcnt 2K][boff 2K unused][gcursor 2K][rowptr (N+4)*4][recs E*4]
  // [colsrc E*4][xw1b 16N*2][xr1 16N*4][hb 16N*2]
  char* w = (char*)d_ws;
  int* bcnt = (int*)w;           w += 2048;
  int* boff = (int*)w;           w += 2048;  // retained for layout stability
  int* gcursor = (int*)w;        w += 2048;
  int* rowptr = (int*)w;         w += (size_t)(N_NODES + 4) * 4;
  unsigned* recs = (unsigned*)w; w += (size_t)NEDGE * 4;
  int* colsrc = (int*)w;         w += (size_t)NEDGE * 4;
  unsigned* xw1b = (unsigned*)w; w += (size_t)N_NODES * HID * 2;
  float* xr1 = (float*)w;        w += (size_t)N_NODES * HID * 4;
  unsigned* hbu = (unsigned*)w;  w += (size_t)N_NODES * HID * 2;
  (void)boff;

  // zero bcnt + (unused boff) + gcursor in one call
  hipMemsetAsync(bcnt, 0, 6144, stream);

  histB_kernel<<<NCHUNK, 512, 0, stream>>>(dstp, bcnt);
  mid_kernel<<<NCHUNK + PROJB, 512, 0, stream>>>(src, dstp, bcnt, gcursor,
                                                 recs, x, W1, root1, xw1b,
                                                 xr1);
  sortB_kernel<<<NBUCK, 1024, 0, stream>>>(bcnt, recs, rowptr, colsrc);
  gather1_kernel<<<(N_NODES * 8 + 255) / 256, 256, 0, stream>>>(
      rowptr, colsrc, (const uint4*)xw1b, (const float4*)xr1, b1,
      (uint4*)hbu);
  g2out_kernel<<<(N_NODES + 31) / 32, 256, 0, stream>>>(
      rowptr, colsrc, (const uint4*)hbu, hbu, W2, root2, b2v, out);
}